// Round 1
// baseline (6870.679 us; speedup 1.0000x reference)
//
#include <hip/hip_runtime.h>
#include <hip/hip_bf16.h>

typedef short bf16x8 __attribute__((ext_vector_type(8)));
typedef float f32x4 __attribute__((ext_vector_type(4)));

constexpr int D_  = 768;
constexpr int FF_ = 3072;
constexpr int HH  = 12;      // heads
constexpr int NT_ = 197;     // tokens
constexpr int BB  = 64;      // batch
constexpr int BR  = BB * NT_;   // 12608 real rows
constexpr int MP  = 12672;      // padded rows (99*128)
constexpr int SN  = 224;        // padded sequence (keys/queries)
constexpr float SCALE_ = 0.125f; // 64^-0.5

__device__ __forceinline__ void gload_lds16(const __hip_bfloat16* g, __hip_bfloat16* l) {
  __builtin_amdgcn_global_load_lds((const __attribute__((address_space(1))) void*)g,
                                   (__attribute__((address_space(3))) void*)l, 16, 0, 0);
}

// ---------------- small kernels ----------------

__global__ void patch_build(const float* __restrict__ x, __hip_bfloat16* __restrict__ p) {
  int e = blockIdx.x * 256 + threadIdx.x;   // each thread: 4 consecutive pj
  int idx4 = e * 4;
  int col = idx4 % 768; int m = idx4 / 768;
  int c = col >> 8; int pi = (col >> 4) & 15; int pj = col & 15;
  int b = m / 196; int s = m - b * 196; int wi = s / 14; int wj = s - wi * 14;
  const float* src = x + (((size_t)b * 3 + c) * 224 + wi * 16 + pi) * 224 + wj * 16 + pj;
  float4 v = *(const float4*)src;
  __hip_bfloat16* dst = p + (size_t)idx4;
  dst[0] = __float2bfloat16(v.x);
  dst[1] = __float2bfloat16(v.y);
  dst[2] = __float2bfloat16(v.z);
  dst[3] = __float2bfloat16(v.w);
}

__global__ void cls_pos(const float* __restrict__ cls_tok, const float* __restrict__ pos, float* __restrict__ t) {
  int e = blockIdx.x * 256 + threadIdx.x;  // 64*768
  int b = e / 768, c = e - (e / 768) * 768;
  t[(size_t)(b * NT_) * D_ + c] = cls_tok[c] + pos[c];
}

__global__ void cvt_bf16(const float* __restrict__ in, __hip_bfloat16* __restrict__ out) {
  int e = blockIdx.x * 256 + threadIdx.x;
  float4 v = ((const float4*)in)[e];
  union { __hip_bfloat16 h[4]; short4 s4; } u;
  u.h[0] = __float2bfloat16(v.x); u.h[1] = __float2bfloat16(v.y);
  u.h[2] = __float2bfloat16(v.z); u.h[3] = __float2bfloat16(v.w);
  ((short4*)out)[e] = u.s4;
}

__global__ void build_bias(const float* __restrict__ rpb, float* __restrict__ bias_all) {
  int e = blockIdx.x * 256 + threadIdx.x;   // 12*224*224 threads
  int j = e % SN; int rest = e / SN; int i = rest % SN; int l = rest / SN;
  int idx;
  if (i >= 197 || j >= 197) idx = 0;
  else if (i == 0 && j == 0) idx = 731;
  else if (i == 0) idx = 729;
  else if (j == 0) idx = 730;
  else {
    int pi = i - 1, pj = j - 1;
    int ri = pi / 14, ci = pi - ri * 14, rj = pj / 14, cj = pj - rj * 14;
    idx = (ri - rj + 13) * 27 + (ci - cj + 13);
  }
  const float* src = rpb + ((size_t)l * 732 + idx) * HH;
  float* dst = bias_all + ((size_t)l * HH * SN + i) * SN + j;
  #pragma unroll
  for (int h = 0; h < HH; ++h) dst[(size_t)h * SN * SN] = src[h];
}

__device__ __forceinline__ void block_reduce2(float& s, float& q, int tid) {
  #pragma unroll
  for (int d = 32; d >= 1; d >>= 1) { s += __shfl_xor(s, d); q += __shfl_xor(q, d); }
  __shared__ float ss[4], qq[4];
  int wave = tid >> 6, lane = tid & 63;
  if (lane == 0) { ss[wave] = s; qq[wave] = q; }
  __syncthreads();
  s = ss[0] + ss[1] + ss[2] + ss[3];
  q = qq[0] + qq[1] + qq[2] + qq[3];
}

__global__ __launch_bounds__(256) void ln_rows(const float* __restrict__ t, const float* __restrict__ w,
                                               const float* __restrict__ b, __hip_bfloat16* __restrict__ out) {
  int row = blockIdx.x; int tid = threadIdx.x;
  const float* x = t + (size_t)row * D_;
  float v0 = x[tid], v1 = x[tid + 256], v2 = x[tid + 512];
  float s = v0 + v1 + v2;
  float q = v0 * v0 + v1 * v1 + v2 * v2;
  block_reduce2(s, q, tid);
  float mu = s * (1.0f / 768.0f);
  float var = q * (1.0f / 768.0f) - mu * mu;
  float rs = rsqrtf(var + 1e-5f);
  __hip_bfloat16* o = out + (size_t)row * D_;
  o[tid]       = __float2bfloat16((v0 - mu) * rs * w[tid]       + b[tid]);
  o[tid + 256] = __float2bfloat16((v1 - mu) * rs * w[tid + 256] + b[tid + 256]);
  o[tid + 512] = __float2bfloat16((v2 - mu) * rs * w[tid + 512] + b[tid + 512]);
}

__global__ __launch_bounds__(256) void pool_ln(const float* __restrict__ t, const float* __restrict__ w,
                                               const float* __restrict__ b, float* __restrict__ out) {
  int bimg = blockIdx.x; int tid = threadIdx.x;
  const float* base = t + ((size_t)bimg * NT_ + 1) * D_;
  float a0 = 0.f, a1 = 0.f, a2 = 0.f;
  for (int s = 0; s < 196; ++s) {
    const float* r = base + (size_t)s * D_;
    a0 += r[tid]; a1 += r[tid + 256]; a2 += r[tid + 512];
  }
  a0 *= (1.0f / 196.0f); a1 *= (1.0f / 196.0f); a2 *= (1.0f / 196.0f);
  float s = a0 + a1 + a2;
  float q = a0 * a0 + a1 * a1 + a2 * a2;
  block_reduce2(s, q, tid);
  float mu = s * (1.0f / 768.0f);
  float var = q * (1.0f / 768.0f) - mu * mu;
  float rs = rsqrtf(var + 1e-5f);
  float* o = out + (size_t)bimg * D_;
  o[tid]       = (a0 - mu) * rs * w[tid]       + b[tid];
  o[tid + 256] = (a1 - mu) * rs * w[tid + 256] + b[tid + 256];
  o[tid + 512] = (a2 - mu) * rs * w[tid + 512] + b[tid + 512];
}

// ---------------- GEMM: C = A @ W^T, fused epilogues ----------------

enum { EPI_PATCH = 0, EPI_QKV = 1, EPI_GELU = 2, EPI_RESID = 3 };

struct GemmArgs {
  const __hip_bfloat16* A;
  const __hip_bfloat16* W;
  int K;
  int NTILES;
  const float* bias;
  const float* bias2;
  const float* gamma;
  const float* pos;
  float* tout;
  __hip_bfloat16* out;
  __hip_bfloat16* qo;
  __hip_bfloat16* ko;
  __hip_bfloat16* vo;
};

template <int MODE>
__global__ __launch_bounds__(256) void gemm_bt(GemmArgs p) {
  const int tid = threadIdx.x, lane = tid & 63, wave = tid >> 6;
  const int wr = wave >> 1, wc = wave & 1;
  const int bn = blockIdx.x % p.NTILES, bm = blockIdx.x / p.NTILES;
  __shared__ __align__(16) __hip_bfloat16 As[128 * 32];
  __shared__ __align__(16) __hip_bfloat16 Bs[128 * 32];
  f32x4 acc[4][4] = {};
  const int K = p.K;
  const __hip_bfloat16* Abase = p.A + (size_t)bm * 128 * K;
  const __hip_bfloat16* Wbase = p.W + (size_t)bn * 128 * K;
  const int rowA = tid >> 2, kc = (tid & 3) * 8;
  const int l15 = lane & 15, l4 = lane >> 4;
  for (int k0 = 0; k0 < K; k0 += 32) {
    gload_lds16(Abase + (size_t)rowA * K + k0 + kc,        As + (size_t)(wave * 64) * 8);
    gload_lds16(Abase + (size_t)(rowA + 64) * K + k0 + kc, As + (size_t)(256 + wave * 64) * 8);
    gload_lds16(Wbase + (size_t)rowA * K + k0 + kc,        Bs + (size_t)(wave * 64) * 8);
    gload_lds16(Wbase + (size_t)(rowA + 64) * K + k0 + kc, Bs + (size_t)(256 + wave * 64) * 8);
    __syncthreads();
    bf16x8 af[4], bfr[4];
    #pragma unroll
    for (int i = 0; i < 4; ++i) {
      af[i]  = *(const bf16x8*)&As[(wr * 64 + i * 16 + l15) * 32 + l4 * 8];
      bfr[i] = *(const bf16x8*)&Bs[(wc * 64 + i * 16 + l15) * 32 + l4 * 8];
    }
    #pragma unroll
    for (int i = 0; i < 4; ++i)
      #pragma unroll
      for (int j = 0; j < 4; ++j)
        acc[i][j] = __builtin_amdgcn_mfma_f32_16x16x32_bf16(af[i], bfr[j], acc[i][j], 0, 0, 0);
    __syncthreads();
  }
  const int mb = bm * 128 + wr * 64, nb = bn * 128 + wc * 64;
  #pragma unroll
  for (int i = 0; i < 4; ++i) {
    #pragma unroll
    for (int j = 0; j < 4; ++j) {
      #pragma unroll
      for (int r = 0; r < 4; ++r) {
        int m = mb + i * 16 + l4 * 4 + r;
        int n = nb + j * 16 + l15;
        float v = acc[i][j][r];
        if constexpr (MODE == EPI_PATCH) {
          int b = m / 196, s = m - (m / 196) * 196;
          int dst = b * NT_ + s + 1;
          p.tout[(size_t)dst * D_ + n] = v + p.bias[n] + p.pos[(size_t)(s + 1) * D_ + n];
        } else if constexpr (MODE == EPI_QKV) {
          if (m < BR) {
            int b = m / NT_, nn = m - (m / NT_) * NT_;
            int which = n / D_, d = n - which * D_;
            int head = d >> 6, hd = d & 63;
            if (which == 0)
              p.qo[(((size_t)(b * HH + head)) * SN + nn) * 64 + hd] = __float2bfloat16((v + p.bias[d]) * SCALE_);
            else if (which == 1)
              p.ko[(((size_t)(b * HH + head)) * SN + nn) * 64 + hd] = __float2bfloat16(v);
            else
              p.vo[(((size_t)(b * HH + head)) * 64 + hd) * SN + nn] = __float2bfloat16(v + p.bias2[d]);
          }
        } else if constexpr (MODE == EPI_GELU) {
          float xg = v + p.bias[n];
          float g = 0.5f * xg * (1.0f + erff(xg * 0.70710678118654752f));
          p.out[(size_t)m * FF_ + n] = __float2bfloat16(g);
        } else {  // EPI_RESID
          if (m < BR) {
            size_t off = (size_t)m * D_ + n;
            p.tout[off] += p.gamma[n] * (v + p.bias[n]);
          }
        }
      }
    }
  }
}

// ---------------- attention ----------------

__global__ __launch_bounds__(256) void attn_kernel(const __hip_bfloat16* __restrict__ qb,
    const __hip_bfloat16* __restrict__ kb, const __hip_bfloat16* __restrict__ vtb,
    const float* __restrict__ biasL, __hip_bfloat16* __restrict__ o) {
  int bh = blockIdx.x; int b = bh / HH, h = bh - b * HH;
  int lane = threadIdx.x & 63, wave = threadIdx.x >> 6;
  int l15 = lane & 15, l4 = lane >> 4;
  __shared__ __align__(16) __hip_bfloat16 probs[4][16][SN];
  const __hip_bfloat16* Q  = qb  + (size_t)bh * SN * 64;
  const __hip_bfloat16* Kp = kb  + (size_t)bh * SN * 64;
  const __hip_bfloat16* VT = vtb + (size_t)bh * 64 * SN;
  const float* BIAS = biasL + (size_t)h * SN * SN;
  for (int mt = wave; mt < 13; mt += 4) {
    int m0 = mt * 16;
    bf16x8 qf0 = *(const bf16x8*)(Q + ((size_t)(m0 + l15)) * 64 + l4 * 8);
    bf16x8 qf1 = *(const bf16x8*)(Q + ((size_t)(m0 + l15)) * 64 + 32 + l4 * 8);
    f32x4 sc[14] = {};
    #pragma unroll
    for (int nt = 0; nt < 14; ++nt) {
      bf16x8 kf0 = *(const bf16x8*)(Kp + ((size_t)(nt * 16 + l15)) * 64 + l4 * 8);
      bf16x8 kf1 = *(const bf16x8*)(Kp + ((size_t)(nt * 16 + l15)) * 64 + 32 + l4 * 8);
      sc[nt] = __builtin_amdgcn_mfma_f32_16x16x32_bf16(qf0, kf0, sc[nt], 0, 0, 0);
      sc[nt] = __builtin_amdgcn_mfma_f32_16x16x32_bf16(qf1, kf1, sc[nt], 0, 0, 0);
    }
    float rmax[4] = {-1e30f, -1e30f, -1e30f, -1e30f};
    #pragma unroll
    for (int nt = 0; nt < 14; ++nt) {
      int j = nt * 16 + l15;
      #pragma unroll
      for (int r = 0; r < 4; ++r) {
        int i = m0 + l4 * 4 + r;
        float v = (j < 197) ? (sc[nt][r] + BIAS[i * SN + j]) : -1e30f;
        sc[nt][r] = v;
        rmax[r] = fmaxf(rmax[r], v);
      }
    }
    #pragma unroll
    for (int r = 0; r < 4; ++r)
      #pragma unroll
      for (int d = 1; d < 16; d <<= 1)
        rmax[r] = fmaxf(rmax[r], __shfl_xor(rmax[r], d));
    float rsum[4] = {0.f, 0.f, 0.f, 0.f};
    #pragma unroll
    for (int nt = 0; nt < 14; ++nt)
      #pragma unroll
      for (int r = 0; r < 4; ++r) {
        float e = __expf(sc[nt][r] - rmax[r]);
        sc[nt][r] = e;
        rsum[r] += e;
      }
    #pragma unroll
    for (int r = 0; r < 4; ++r) {
      #pragma unroll
      for (int d = 1; d < 16; d <<= 1) rsum[r] += __shfl_xor(rsum[r], d);
      rsum[r] = 1.0f / rsum[r];
    }
    #pragma unroll
    for (int nt = 0; nt < 14; ++nt)
      #pragma unroll
      for (int r = 0; r < 4; ++r)
        probs[wave][l4 * 4 + r][nt * 16 + l15] = __float2bfloat16(sc[nt][r] * rsum[r]);
    asm volatile("s_waitcnt lgkmcnt(0)" ::: "memory");
    __builtin_amdgcn_sched_barrier(0);
    f32x4 oc[4] = {};
    #pragma unroll
    for (int kt = 0; kt < 7; ++kt) {
      bf16x8 pf = *(const bf16x8*)&probs[wave][l15][kt * 32 + l4 * 8];
      #pragma unroll
      for (int nt = 0; nt < 4; ++nt) {
        bf16x8 vf = *(const bf16x8*)(VT + ((size_t)(nt * 16 + l15)) * SN + kt * 32 + l4 * 8);
        oc[nt] = __builtin_amdgcn_mfma_f32_16x16x32_bf16(pf, vf, oc[nt], 0, 0, 0);
      }
    }
    #pragma unroll
    for (int nt = 0; nt < 4; ++nt)
      #pragma unroll
      for (int r = 0; r < 4; ++r) {
        int i = m0 + l4 * 4 + r;
        if (i < 197)
          o[((size_t)(b * NT_ + i)) * D_ + h * 64 + nt * 16 + l15] = __float2bfloat16(oc[nt][r]);
      }
  }
}

// ---------------- host ----------------

extern "C" void kernel_launch(void* const* d_in, const int* in_sizes, int n_in,
                              void* d_out, int out_size, void* d_ws, size_t ws_size,
                              hipStream_t stream) {
  const float* x       = (const float*)d_in[0];
  const float* patch_w = (const float*)d_in[1];
  const float* patch_b = (const float*)d_in[2];
  const float* cls_tok = (const float*)d_in[3];
  const float* pos_emb = (const float*)d_in[4];
  const float* ln1_w   = (const float*)d_in[5];
  const float* ln1_b   = (const float*)d_in[6];
  const float* qkv_w   = (const float*)d_in[7];
  const float* q_bias  = (const float*)d_in[8];
  const float* v_bias  = (const float*)d_in[9];
  const float* proj_w  = (const float*)d_in[10];
  const float* proj_b  = (const float*)d_in[11];
  const float* ln2_w   = (const float*)d_in[12];
  const float* ln2_b   = (const float*)d_in[13];
  const float* fc1_w   = (const float*)d_in[14];
  const float* fc1_b   = (const float*)d_in[15];
  const float* fc2_w   = (const float*)d_in[16];
  const float* fc2_b   = (const float*)d_in[17];
  const float* gamma1  = (const float*)d_in[18];
  const float* gamma2  = (const float*)d_in[19];
  const float* rpb     = (const float*)d_in[20];
  const float* fcn_w   = (const float*)d_in[21];
  const float* fcn_b   = (const float*)d_in[22];
  float* out = (float*)d_out;

  char* ws = (char*)d_ws;
  size_t off = 0;
  auto alloc = [&](size_t bytes) -> void* {
    void* p = ws + off;
    off = (off + bytes + 255) & ~(size_t)255;
    return p;
  };
  float* t            = (float*)alloc((size_t)MP * D_ * 4);
  __hip_bfloat16* h   = (__hip_bfloat16*)alloc((size_t)MP * D_ * 2);
  __hip_bfloat16* ob  = (__hip_bfloat16*)alloc((size_t)MP * D_ * 2);
  __hip_bfloat16* mid = (__hip_bfloat16*)alloc((size_t)MP * FF_ * 2);   // also patch matrix p
  __hip_bfloat16* qb  = (__hip_bfloat16*)alloc((size_t)BB * HH * SN * 64 * 2);
  __hip_bfloat16* kb  = (__hip_bfloat16*)alloc((size_t)BB * HH * SN * 64 * 2);
  __hip_bfloat16* vtb = (__hip_bfloat16*)alloc((size_t)BB * HH * 64 * SN * 2);
  float* bias_all     = (float*)alloc((size_t)12 * HH * SN * SN * 4);
  __hip_bfloat16* wq  = (__hip_bfloat16*)alloc((size_t)2304 * 768 * 2);
  __hip_bfloat16* wp  = (__hip_bfloat16*)alloc((size_t)768 * 768 * 2);
  __hip_bfloat16* w1  = (__hip_bfloat16*)alloc((size_t)3072 * 768 * 2);
  __hip_bfloat16* w2  = (__hip_bfloat16*)alloc((size_t)768 * 3072 * 2);
  __hip_bfloat16* wpt = (__hip_bfloat16*)alloc((size_t)768 * 768 * 2);

  patch_build<<<9408, 256, 0, stream>>>(x, mid);
  cvt_bf16<<<576, 256, 0, stream>>>(patch_w, wpt);
  cls_pos<<<192, 256, 0, stream>>>(cls_tok, pos_emb, t);
  build_bias<<<2352, 256, 0, stream>>>(rpb, bias_all);
  {
    GemmArgs g = {};
    g.A = mid; g.W = wpt; g.K = 768; g.NTILES = 6;
    g.bias = patch_b; g.pos = pos_emb; g.tout = t;
    gemm_bt<EPI_PATCH><<<98 * 6, 256, 0, stream>>>(g);
  }
  for (int l = 0; l < 12; ++l) {
    cvt_bf16<<<1728, 256, 0, stream>>>(qkv_w + (size_t)l * 2304 * 768, wq);
    ln_rows<<<BR, 256, 0, stream>>>(t, ln1_w + l * 768, ln1_b + l * 768, h);
    {
      GemmArgs g = {};
      g.A = h; g.W = wq; g.K = 768; g.NTILES = 18;
      g.bias = q_bias + l * 768; g.bias2 = v_bias + l * 768;
      g.qo = qb; g.ko = kb; g.vo = vtb;
      gemm_bt<EPI_QKV><<<99 * 18, 256, 0, stream>>>(g);
    }
    attn_kernel<<<768, 256, 0, stream>>>(qb, kb, vtb, bias_all + (size_t)l * HH * SN * SN, ob);
    cvt_bf16<<<576, 256, 0, stream>>>(proj_w + (size_t)l * 768 * 768, wp);
    {
      GemmArgs g = {};
      g.A = ob; g.W = wp; g.K = 768; g.NTILES = 6;
      g.bias = proj_b + l * 768; g.gamma = gamma1 + l * 768; g.tout = t;
      gemm_bt<EPI_RESID><<<99 * 6, 256, 0, stream>>>(g);
    }
    ln_rows<<<BR, 256, 0, stream>>>(t, ln2_w + l * 768, ln2_b + l * 768, h);
    cvt_bf16<<<2304, 256, 0, stream>>>(fc1_w + (size_t)l * 3072 * 768, w1);
    {
      GemmArgs g = {};
      g.A = h; g.W = w1; g.K = 768; g.NTILES = 24;
      g.bias = fc1_b + l * 3072; g.out = mid;
      gemm_bt<EPI_GELU><<<99 * 24, 256, 0, stream>>>(g);
    }
    cvt_bf16<<<2304, 256, 0, stream>>>(fc2_w + (size_t)l * 768 * 3072, w2);
    {
      GemmArgs g = {};
      g.A = mid; g.W = w2; g.K = 3072; g.NTILES = 6;
      g.bias = fc2_b + l * 768; g.gamma = gamma2 + l * 768; g.tout = t;
      gemm_bt<EPI_RESID><<<99 * 6, 256, 0, stream>>>(g);
    }
  }
  pool_ln<<<64, 256, 0, stream>>>(t, fcn_w, fcn_b, out);
}